// Round 1
// baseline (633.192 us; speedup 1.0000x reference)
//
#include <hip/hip_runtime.h>
#include <hip/hip_bf16.h>

// Problem constants
#define B_ 16
#define L_ 1024
#define H_ 1024
#define N_ 64
// M = B*L = 16384, K = H = 1024, output cols = 2H = 2048 (a|g pairs)

typedef __bf16 bf16x8 __attribute__((ext_vector_type(8)));
typedef float  f32x4  __attribute__((ext_vector_type(4)));

// async global->LDS, 16B per lane; LDS dest is wave-uniform base + lane*16
__device__ __forceinline__ void gll16(const void* g, void* l) {
    __builtin_amdgcn_global_load_lds(
        (const __attribute__((address_space(1))) unsigned int*)g,
        (__attribute__((address_space(3))) unsigned int*)l,
        16, 0, 0);
}

// ---------------------------------------------------------------------------
// K0: per-(h,n) discretization: w = exp(dt*A), c2 = 2*C*(exp(dt*A)-1)/A
// packed as float4 {wr, wi, 2cr, 2ci}
// ---------------------------------------------------------------------------
__global__ __launch_bounds__(256) void setup_wcoef(
        const float* __restrict__ log_dt, const float* __restrict__ Arl,
        const float* __restrict__ Aim, const float* __restrict__ Cr,
        const float* __restrict__ Ci, float4* __restrict__ wcoef) {
    int i = blockIdx.x * 256 + threadIdx.x;   // < H*N = 65536
    int h = i >> 6;
    float dt = expf(log_dt[h]);
    float ar = -expf(Arl[i]);
    float ai = Aim[i];
    float dr = dt * ar, di = dt * ai;
    float e  = expf(dr);
    float wr = e * cosf(di), wi = e * sinf(di);
    float em1r = wr - 1.0f, em1i = wi;          // exp(dtA) - 1
    float cr = Cr[i], ci = Ci[i];
    float tr = cr * em1r - ci * em1i;           // C * (exp(dtA)-1)
    float ti = cr * em1i + ci * em1r;
    float inv = 1.0f / (ar * ar + ai * ai);     // |A|^2 >= 0.25
    float kr = (tr * ar + ti * ai) * inv;       // t / A  (via conj)
    float ki = (ti * ar - tr * ai) * inv;
    wcoef[i] = make_float4(wr, wi, 2.0f * kr, 2.0f * ki);
}

// ---------------------------------------------------------------------------
// K1: x [B,L,H] f32 -> xT [B*H, L] f32  (coalesced scan reads)
// ---------------------------------------------------------------------------
__global__ __launch_bounds__(1024) void transpose_x(
        const float* __restrict__ x, float* __restrict__ xT) {
    __shared__ float t[32][33];
    int b = blockIdx.z, h0 = blockIdx.x * 32, l0 = blockIdx.y * 32;
    t[threadIdx.y][threadIdx.x] =
        x[b * (L_ * H_) + (l0 + threadIdx.y) * H_ + h0 + threadIdx.x];
    __syncthreads();
    xT[(b * H_ + h0 + threadIdx.y) * L_ + l0 + threadIdx.x] =
        t[threadIdx.x][threadIdx.y];
}

// ---------------------------------------------------------------------------
// K2: diagonal-SSM scan + D-skip + tanh-GELU, writes yT_act [B*H, L] bf16
// 4 seqs per wave (16 lanes each), 4 complex states per lane (N=64)
// ---------------------------------------------------------------------------
__global__ __launch_bounds__(256) void scan_kernel(
        const float* __restrict__ xT, const float4* __restrict__ wc,
        const float* __restrict__ Dv, __hip_bfloat16* __restrict__ yTa) {
    int tid  = threadIdx.x;
    int wave = blockIdx.x * 4 + (tid >> 6);
    int lane = tid & 63;
    int grp = lane >> 4, l16 = lane & 15;
    int sq  = wave * 4 + grp;                // b*H + h
    int h   = sq & (H_ - 1);

    float wr[4], wi[4], c2r[4], c2i[4], sr[4], si[4];
#pragma unroll
    for (int j = 0; j < 4; ++j) {
        float4 v = wc[h * N_ + l16 + j * 16];
        wr[j] = v.x; wi[j] = v.y; c2r[j] = v.z; c2i[j] = v.w;
        sr[j] = 0.0f; si[j] = 0.0f;
    }
    float Dh = Dv[h];
    const float* xp = xT + (size_t)sq * L_;
    __hip_bfloat16* yp = yTa + (size_t)sq * L_;
    int bbase = lane & 48;                   // group base for broadcast

#pragma unroll 1
    for (int ch = 0; ch < 64; ++ch) {
        float xv = xp[ch * 16 + l16];        // lane t holds x[l0+t]
        float yreg = 0.0f;
#pragma unroll
        for (int t = 0; t < 16; ++t) {
            float xl = __shfl(xv, bbase | t, 64);
            float acc = 0.0f;
#pragma unroll
            for (int j = 0; j < 4; ++j) {
                float nr = wr[j] * sr[j] - wi[j] * si[j] + xl;
                float ni = wr[j] * si[j] + wi[j] * sr[j];
                sr[j] = nr; si[j] = ni;
                acc += c2r[j] * nr;
                acc -= c2i[j] * ni;
            }
            acc += __shfl_xor(acc, 1, 64);
            acc += __shfl_xor(acc, 2, 64);
            acc += __shfl_xor(acc, 4, 64);
            acc += __shfl_xor(acc, 8, 64);
            if (l16 == t) yreg = acc;
        }
        float yv = yreg + xv * Dh;           // D skip
        float u  = yv + 0.044715f * yv * yv * yv;   // tanh GELU (jax default)
        float g  = 0.5f * yv * (1.0f + tanhf(0.7978845608028654f * u));
        yp[ch * 16 + l16] = __float2bfloat16(g);
    }
}

// ---------------------------------------------------------------------------
// K3: yT_act [B*H, L] bf16 -> Y [B*L, H] bf16 (GEMM A, k-contiguous rows)
// ---------------------------------------------------------------------------
__global__ __launch_bounds__(1024) void transpose_y(
        const unsigned short* __restrict__ yT, unsigned short* __restrict__ Y) {
    __shared__ unsigned short t[32][33];
    int b = blockIdx.z, h0 = blockIdx.x * 32, l0 = blockIdx.y * 32;
    t[threadIdx.y][threadIdx.x] =
        yT[(b * H_ + h0 + threadIdx.y) * L_ + l0 + threadIdx.x];
    __syncthreads();
    Y[(b * L_ + l0 + threadIdx.y) * H_ + h0 + threadIdx.x] =
        t[threadIdx.x][threadIdx.y];
}

// ---------------------------------------------------------------------------
// K4a: W [K=1024, 2048] f32 -> Wt [2048, K] bf16 (GEMM B, k-contiguous rows)
// ---------------------------------------------------------------------------
__global__ __launch_bounds__(1024) void transpose_w(
        const float* __restrict__ W, __hip_bfloat16* __restrict__ Wt) {
    __shared__ float t[32][33];
    int n0 = blockIdx.x * 32, k0 = blockIdx.y * 32;
    t[threadIdx.y][threadIdx.x] = W[(k0 + threadIdx.y) * 2048 + n0 + threadIdx.x];
    __syncthreads();
    Wt[(n0 + threadIdx.y) * H_ + k0 + threadIdx.x] =
        __float2bfloat16(t[threadIdx.x][threadIdx.y]);
}

// ---------------------------------------------------------------------------
// K4: Z = Y @ Wt^T (+b), fused GLU epilogue: out = za * sigmoid(zg)
// BM=128, BN=64 h-cols (block computes cols h and h+1024 together), BK=64
// 4 waves: 2x2, wave tile 64m x 32n(a)+32n(g). 16x16x32 bf16 MFMA.
// LDS xor-swizzle: chunk_phys = chunk_log ^ (row&7), compatible with
// global_load_lds's uniform-base+lane*16 constraint (swizzle on src addr).
// ---------------------------------------------------------------------------
__global__ __launch_bounds__(256, 2) void gemm_glu(
        const __hip_bfloat16* __restrict__ Y, const __hip_bfloat16* __restrict__ Wt,
        const float* __restrict__ bv, float* __restrict__ out) {
    __shared__ char lds[32768];
    char* sA  = lds;             // [128 rows][8 chunks * 16B] = 16 KiB
    char* sBa = lds + 16384;     // [64][128B] = 8 KiB
    char* sBg = lds + 24576;     // [64][128B] = 8 KiB

    int tid = threadIdx.x, wv = tid >> 6, lane = tid & 63;
    int mb = (blockIdx.x & 127) * 128;       // m-block
    int h0 = (blockIdx.x >> 7) * 64;         // h-block
    int r8 = lane >> 3, c8 = lane & 7, csrc = c8 ^ r8;
    int wm = (wv >> 1) * 64, wn = (wv & 1) * 32;
    int lm = lane & 15, q = lane >> 4;

    const char* Yb = (const char*)Y;
    const char* Wb = (const char*)Wt;

    f32x4 accA[4][2], accG[4][2];
#pragma unroll
    for (int i = 0; i < 4; ++i)
#pragma unroll
        for (int j = 0; j < 2; ++j) {
            accA[i][j] = (f32x4){0.f, 0.f, 0.f, 0.f};
            accG[i][j] = (f32x4){0.f, 0.f, 0.f, 0.f};
        }

    for (int kt = 0; kt < 16; ++kt) {
        int k0b = kt * 128;                  // byte offset into 2048B rows
        __syncthreads();                     // prev compute done with LDS
        // stage A: 16 wave-loads of 8 rows each, this wave does 4
#pragma unroll
        for (int j = 0; j < 4; ++j) {
            int i = wv * 4 + j;
            gll16(Yb + (size_t)(mb + i * 8 + r8) * 2048 + k0b + csrc * 16,
                  sA + i * 1024);
        }
#pragma unroll
        for (int j = 0; j < 2; ++j) {
            int i = wv * 2 + j;
            int n = h0 + i * 8 + r8;
            gll16(Wb + (size_t)n * 2048 + k0b + csrc * 16, sBa + i * 1024);
            gll16(Wb + (size_t)(n + 1024) * 2048 + k0b + csrc * 16, sBg + i * 1024);
        }
        __syncthreads();                     // vmcnt(0) drained before barrier
#pragma unroll
        for (int kk = 0; kk < 2; ++kk) {
            int clog = kk * 4 + q;
            bf16x8 af[4], ba[2], bg[2];
#pragma unroll
            for (int mt = 0; mt < 4; ++mt) {
                int m = wm + mt * 16 + lm;
                af[mt] = *(const bf16x8*)(sA + m * 128 + ((clog ^ (m & 7)) * 16));
            }
#pragma unroll
            for (int nt = 0; nt < 2; ++nt) {
                int n = wn + nt * 16 + lm;
                int cph = (clog ^ (n & 7)) * 16;
                ba[nt] = *(const bf16x8*)(sBa + n * 128 + cph);
                bg[nt] = *(const bf16x8*)(sBg + n * 128 + cph);
            }
#pragma unroll
            for (int mt = 0; mt < 4; ++mt)
#pragma unroll
                for (int nt = 0; nt < 2; ++nt) {
                    accA[mt][nt] = __builtin_amdgcn_mfma_f32_16x16x32_bf16(
                        af[mt], ba[nt], accA[mt][nt], 0, 0, 0);
                    accG[mt][nt] = __builtin_amdgcn_mfma_f32_16x16x32_bf16(
                        af[mt], bg[nt], accG[mt][nt], 0, 0, 0);
                }
        }
    }
    // epilogue: C/D frag mapping col=lane&15, row=(lane>>4)*4+r
#pragma unroll
    for (int mt = 0; mt < 4; ++mt)
#pragma unroll
        for (int nt = 0; nt < 2; ++nt) {
            int hc = h0 + wn + nt * 16 + lm;
            float bba = bv[hc], bbg = bv[hc + 1024];
#pragma unroll
            for (int r = 0; r < 4; ++r) {
                int m = mb + wm + mt * 16 + q * 4 + r;
                float za = accA[mt][nt][r] + bba;
                float zg = accG[mt][nt][r] + bbg;
                out[(size_t)m * H_ + hc] = za / (1.0f + expf(-zg));
            }
        }
}

// ---------------------------------------------------------------------------
extern "C" void kernel_launch(void* const* d_in, const int* in_sizes, int n_in,
                              void* d_out, int out_size, void* d_ws, size_t ws_size,
                              hipStream_t stream) {
    const float* x      = (const float*)d_in[0];
    const float* log_dt = (const float*)d_in[1];
    const float* Arl    = (const float*)d_in[2];
    const float* Aim    = (const float*)d_in[3];
    const float* Cr     = (const float*)d_in[4];
    const float* Ci     = (const float*)d_in[5];
    const float* Dv     = (const float*)d_in[6];
    const float* W      = (const float*)d_in[7];
    const float* bv     = (const float*)d_in[8];
    float* out = (float*)d_out;

    char* ws = (char*)d_ws;
    // layout: [0,64M) xT f32 (reused as Y bf16 after scan) | [64M,96M) yT_act
    //         [96M,97M) wcoef | [98M,102M) Wt
    float*           xT    = (float*)ws;
    __hip_bfloat16*  Ybf   = (__hip_bfloat16*)ws;
    __hip_bfloat16*  yTa   = (__hip_bfloat16*)(ws + (64u << 20));
    float4*          wcoef = (float4*)(ws + (96u << 20));
    __hip_bfloat16*  Wt    = (__hip_bfloat16*)(ws + (98u << 20));

    dim3 tb(32, 32);
    setup_wcoef<<<256, 256, 0, stream>>>(log_dt, Arl, Aim, Cr, Ci, wcoef);
    transpose_x<<<dim3(32, 32, 16), tb, 0, stream>>>(x, xT);
    transpose_w<<<dim3(64, 32), tb, 0, stream>>>(W, Wt);
    scan_kernel<<<1024, 256, 0, stream>>>(xT, wcoef, Dv, yTa);
    transpose_y<<<dim3(32, 32, 16), tb, 0, stream>>>(
        (const unsigned short*)yTa, (unsigned short*)Ybf);
    gemm_glu<<<2048, 256, 0, stream>>>(Ybf, Wt, bv, out);
}

// Round 2
// 386.201 us; speedup vs baseline: 1.6395x; 1.6395x over previous
//
#include <hip/hip_runtime.h>
#include <hip/hip_bf16.h>

// Problem constants
#define B_ 16
#define L_ 1024
#define H_ 1024
#define N_ 64
// M = B*L = 16384, K = H = 1024, output cols = 2H = 2048 (a|g pairs)
// Chunked SSM: T=64 chunk, 16 chunks/seq.

typedef __bf16 bf16x8 __attribute__((ext_vector_type(8)));
typedef float  f32x4  __attribute__((ext_vector_type(4)));

// async global->LDS, 16B per lane; LDS dest is wave-uniform base + lane*16
__device__ __forceinline__ void gll16(const void* g, void* l) {
    __builtin_amdgcn_global_load_lds(
        (const __attribute__((address_space(1))) unsigned int*)g,
        (__attribute__((address_space(3))) unsigned int*)l,
        16, 0, 0);
}

__device__ __forceinline__ float gelu_tanh(float yv) {
    float u = yv + 0.044715f * yv * yv * yv;
    return 0.5f * yv * (1.0f + tanhf(0.7978845608028654f * u));
}

// ---------------------------------------------------------------------------
// K0: per-h tables for the chunked scan.
//  Bt [H][192][64] bf16: rows 0..63   = Toeplitz K: Bt[t][j] = k[t-j] (j<=t)
//                        rows 64+ri   = Vandermonde: ri=2n+e ->
//                                       Re/Im(w_n^{63-j}) at col j
//  Qt [H][64][128] bf16: Qt[t][2n]   =  Re(2coef_n w_n^{t+1})
//                        Qt[t][2n+1] = -Im(2coef_n w_n^{t+1})
//  wT [H][N] float2: w^64 (chunk carry multiplier)
// One block per h, 64 threads (n = tid).
// ---------------------------------------------------------------------------
__global__ __launch_bounds__(64) void build_tables(
        const float* __restrict__ log_dt, const float* __restrict__ Arl,
        const float* __restrict__ Aim, const float* __restrict__ Cr,
        const float* __restrict__ Ci,
        __hip_bfloat16* __restrict__ Bt, __hip_bfloat16* __restrict__ Qt,
        float2* __restrict__ wT) {
    __shared__ float cr[64][65], ci[64][65], pwr[64][65], pwi[64][65], kl[64];
    int h = blockIdx.x, n = threadIdx.x;
    int i = h * 64 + n;
    float dt = expf(log_dt[h]);
    float ar = -expf(Arl[i]), ai = Aim[i];
    float dr = dt * ar, di = dt * ai;
    float e  = expf(dr);
    float wr = e * cosf(di), wi = e * sinf(di);
    float em1r = wr - 1.0f, em1i = wi;           // exp(dtA)-1
    float Crv = Cr[i], Civ = Ci[i];
    float tr = Crv * em1r - Civ * em1i;
    float ti = Crv * em1i + Civ * em1r;
    float inv = 1.0f / (ar * ar + ai * ai);
    float c2r = 2.0f * (tr * ar + ti * ai) * inv;  // 2*C*(exp(dtA)-1)/A
    float c2i = 2.0f * (ti * ar - tr * ai) * inv;
    float pr = 1.0f, pi = 0.0f;                  // p = w^j
    for (int j = 0; j < 64; ++j) {
        cr[n][j] = c2r * pr - c2i * pi;          // Re(c2 * w^j)
        ci[n][j] = c2r * pi + c2i * pr;          // Im
        pwr[n][j] = pr; pwi[n][j] = pi;          // w^j
        float nr2 = pr * wr - pi * wi, ni2 = pr * wi + pi * wr;
        pr = nr2; pi = ni2;
    }
    cr[n][64] = c2r * pr - c2i * pi;             // exponent 64 (for Qt t=63)
    ci[n][64] = c2r * pi + c2i * pr;
    wT[i] = make_float2(pr, pi);                 // w^64
    __syncthreads();
    // k[j] = sum_n Re(c2 w^j): thread j sums column j (pad 65 -> no conflict)
    float s = 0.0f;
    for (int m = 0; m < 64; ++m) s += cr[m][n];
    kl[n] = s;
    __syncthreads();
    // Toeplitz rows: thread t=n writes its row
    for (int j = 0; j < 64; ++j)
        Bt[(size_t)(h * 192 + n) * 64 + j] =
            __float2bfloat16(j <= n ? kl[n - j] : 0.0f);
    // Vandermonde rows (coalesced: thread n writes col n of each row)
    for (int rr = 0; rr < 128; ++rr) {
        int nn = rr >> 1;
        float v = (rr & 1) ? pwi[nn][63 - n] : pwr[nn][63 - n];
        Bt[(size_t)(h * 192 + 64 + rr) * 64 + n] = __float2bfloat16(v);
    }
    // Qt rows: per t, threads write ri=n and ri=n+64 (coalesced)
    for (int t = 0; t < 64; ++t) {
        float v0 = (n & 1) ? -ci[n >> 1][t + 1] : cr[n >> 1][t + 1];
        float v1 = (n & 1) ? -ci[(n >> 1) + 32][t + 1] : cr[(n >> 1) + 32][t + 1];
        Qt[(size_t)(h * 64 + t) * 128 + n]      = __float2bfloat16(v0);
        Qt[(size_t)(h * 64 + t) * 128 + n + 64] = __float2bfloat16(v1);
    }
}

// ---------------------------------------------------------------------------
// K1: x [B,L,H] f32 -> xT [B*H, L] f32  (coalesced chunk-scan reads)
// ---------------------------------------------------------------------------
__global__ __launch_bounds__(1024) void transpose_x(
        const float* __restrict__ x, float* __restrict__ xT) {
    __shared__ float t[32][33];
    int b = blockIdx.z, h0 = blockIdx.x * 32, l0 = blockIdx.y * 32;
    t[threadIdx.y][threadIdx.x] =
        x[b * (L_ * H_) + (l0 + threadIdx.y) * H_ + h0 + threadIdx.x];
    __syncthreads();
    xT[(b * H_ + h0 + threadIdx.y) * L_ + l0 + threadIdx.x] =
        t[threadIdx.x][threadIdx.y];
}

// ---------------------------------------------------------------------------
// K2: fused chunked SSM: GEMM1 (conv taps + chunk-local states) -> LDS serial
// chunk scan -> GEMM2 (carry correction) -> D-skip + GELU -> yTa [B*H,L] bf16
// Block: one h, 8 batches (b0 = 0 or 8) -> 128 rows=(b',chunk), 4 waves.
// Wave w: m-strip w*32 (2 m-tiles). Fragment/swizzle conventions identical
// to gemm_glu (phys chunk = logical ^ (row&7), rows 128B for bf16 K=64).
// LDS: phase1 sX[128][128B]@0 16K, sB[192][128B]@16K 24K;
//      phase2 sS f32[128 rows][128 ri]@0 64K (overlays), sQ[64][256B]@64K 16K.
// ---------------------------------------------------------------------------
__global__ __launch_bounds__(256, 2) void chunk_scan(
        const float* __restrict__ xT, const char* __restrict__ Btg,
        const char* __restrict__ Qtg, const float2* __restrict__ wTg,
        const float* __restrict__ Dv, __hip_bfloat16* __restrict__ yTa) {
    __shared__ char lds[81920];
    char* sX = lds;
    char* sB = lds + 16384;
    char* sS = lds;              // f32 [row][ri], swizzled 16B chunks
    char* sQ = lds + 65536;

    int tid = threadIdx.x, wv = tid >> 6, lane = tid & 63;
    int lm = lane & 15, q = lane >> 4, r8 = lane >> 3, c8 = lane & 7;
    int h  = blockIdx.x >> 1;
    int b0 = (blockIdx.x & 1) * 8;

    // ---- stage sB (Bt tables): 24 wave-loads of 8 rows x 128B ----
    int csrc = c8 ^ r8;
#pragma unroll
    for (int j = 0; j < 6; ++j) {
        int i = wv * 6 + j;
        gll16(Btg + ((size_t)(h * 192 + i * 8 + r8)) * 128 + csrc * 16,
              sB + i * 1024);
    }
    // ---- stage sX: xT f32 -> bf16, 8 threads/row, oct=8 f32 each ----
#pragma unroll
    for (int p = 0; p < 4; ++p) {
        int row = p * 32 + (tid >> 3);
        int oct = tid & 7;
        int seq = (b0 + (row >> 4)) * H_ + h;
        const float* gp = xT + (size_t)seq * L_ + (row & 15) * 64 + oct * 8;
        float4 v0 = *(const float4*)gp;
        float4 v1 = *(const float4*)(gp + 4);
        bf16x8 pk;
        pk[0] = (__bf16)v0.x; pk[1] = (__bf16)v0.y;
        pk[2] = (__bf16)v0.z; pk[3] = (__bf16)v0.w;
        pk[4] = (__bf16)v1.x; pk[5] = (__bf16)v1.y;
        pk[6] = (__bf16)v1.z; pk[7] = (__bf16)v1.w;
        *(bf16x8*)(sX + row * 128 + ((oct ^ (row & 7)) * 16)) = pk;
    }
    __syncthreads();

    // ---- GEMM1: acc[2 m][12 n] over K=64 (2 k-steps) ----
    f32x4 acc[2][12];
#pragma unroll
    for (int mt = 0; mt < 2; ++mt)
#pragma unroll
        for (int nt = 0; nt < 12; ++nt) acc[mt][nt] = (f32x4){0.f,0.f,0.f,0.f};

#pragma unroll
    for (int kk = 0; kk < 2; ++kk) {
        int clog = kk * 4 + q;
        bf16x8 af[2];
#pragma unroll
        for (int mt = 0; mt < 2; ++mt) {
            int m = wv * 32 + mt * 16 + lm;
            af[mt] = *(const bf16x8*)(sX + m * 128 + ((clog ^ (m & 7)) * 16));
        }
#pragma unroll
        for (int nt = 0; nt < 12; ++nt) {
            int nrow = nt * 16 + lm;
            bf16x8 bf = *(const bf16x8*)(sB + nrow * 128 + ((clog ^ (nrow & 7)) * 16));
#pragma unroll
            for (int mt = 0; mt < 2; ++mt)
                acc[mt][nt] = __builtin_amdgcn_mfma_f32_16x16x32_bf16(
                    af[mt], bf, acc[mt][nt], 0, 0, 0);
        }
    }
    // ---- issue sQ staging now (region disjoint from sX/sB/sS) ----
#pragma unroll
    for (int j = 0; j < 4; ++j) {
        int i = wv * 4 + j;
        int r4 = lane >> 4, c16 = lane & 15;
        gll16(Qtg + (size_t)(h * 64 + i * 4 + r4) * 256 + (c16 ^ r4) * 16,
              sQ + i * 1024);
    }
    __syncthreads();   // all waves done reading sX/sB; sQ drained too

    // ---- write Sloc tiles (nt 4..11 -> ri 0..127) into sS f32 swizzled ----
    // C layout: col(ri) = lm, row = q*4 + r
#pragma unroll
    for (int mt = 0; mt < 2; ++mt)
#pragma unroll
        for (int nt = 4; nt < 12; ++nt) {
            int ri = (nt - 4) * 16 + lm;
#pragma unroll
            for (int r = 0; r < 4; ++r) {
                int row = wv * 32 + mt * 16 + q * 4 + r;
                *(float*)(sS + row * 512 + (((ri >> 2) ^ (row & 7)) * 16)
                          + (ri & 3) * 4) = acc[mt][nt][r];
            }
        }
    __syncthreads();

    // ---- serial chunk scan in LDS: S_in(c) stored in place of Sloc(c) ----
    {
        int n  = tid & 63, b1 = tid >> 6;
        float2 wt = wTg[h * 64 + n];             // w^64
#pragma unroll
        for (int chain = 0; chain < 2; ++chain) {
            int bp = b1 + chain * 4;
            float s_r = 0.0f, s_i = 0.0f;
#pragma unroll 1
            for (int c = 0; c < 16; ++c) {
                int row = bp * 16 + c;
                char* p = sS + row * 512 + (((n >> 1) ^ (row & 7)) * 16)
                          + (n & 1) * 8;
                float2 loc = *(float2*)p;
                *(float2*)p = make_float2(s_r, s_i);    // S_in before update
                float nr2 = wt.x * s_r - wt.y * s_i + loc.x;
                float ni2 = wt.x * s_i + wt.y * s_r + loc.y;
                s_r = nr2; s_i = ni2;
            }
        }
    }
    __syncthreads();

    // ---- GEMM2: y += S_in[128 x 128] * Qt^T, K=128 (4 k-steps) ----
#pragma unroll
    for (int ks = 0; ks < 4; ++ks) {
        bf16x8 af[2];
#pragma unroll
        for (int mt = 0; mt < 2; ++mt) {
            int row = wv * 32 + mt * 16 + lm;
            int cf0 = ks * 8 + q * 2;
            f32x4 a0 = *(const f32x4*)(sS + row * 512 + ((cf0 ^ (row & 7)) * 16));
            f32x4 a1 = *(const f32x4*)(sS + row * 512 + (((cf0 + 1) ^ (row & 7)) * 16));
            bf16x8 pk;
            pk[0] = (__bf16)a0[0]; pk[1] = (__bf16)a0[1];
            pk[2] = (__bf16)a0[2]; pk[3] = (__bf16)a0[3];
            pk[4] = (__bf16)a1[0]; pk[5] = (__bf16)a1[1];
            pk[6] = (__bf16)a1[2]; pk[7] = (__bf16)a1[3];
            af[mt] = pk;
        }
#pragma unroll
        for (int nt = 0; nt < 4; ++nt) {
            int trow = nt * 16 + lm;
            int c = ks * 4 + q;
            bf16x8 bq = *(const bf16x8*)(sQ + trow * 256 + ((c ^ (trow & 3)) * 16));
#pragma unroll
            for (int mt = 0; mt < 2; ++mt)
                acc[mt][nt] = __builtin_amdgcn_mfma_f32_16x16x32_bf16(
                    af[mt], bq, acc[mt][nt], 0, 0, 0);
        }
    }

    // ---- epilogue: D-skip (f32 x) + GELU -> yTa ----
    float Dh = Dv[h];
#pragma unroll
    for (int mt = 0; mt < 2; ++mt)
#pragma unroll
        for (int nt = 0; nt < 4; ++nt)
#pragma unroll
            for (int r = 0; r < 4; ++r) {
                int row = wv * 32 + mt * 16 + q * 4 + r;
                int seq = (b0 + (row >> 4)) * H_ + h;
                int l   = (row & 15) * 64 + nt * 16 + lm;
                float yv = acc[mt][nt][r] + xT[(size_t)seq * L_ + l] * Dh;
                yTa[(size_t)seq * L_ + l] = __float2bfloat16(gelu_tanh(yv));
            }
}

// ---------------------------------------------------------------------------
// K3: yT_act [B*H, L] bf16 -> Y [B*L, H] bf16 (GEMM A, k-contiguous rows)
// ---------------------------------------------------------------------------
__global__ __launch_bounds__(1024) void transpose_y(
        const unsigned short* __restrict__ yT, unsigned short* __restrict__ Y) {
    __shared__ unsigned short t[32][33];
    int b = blockIdx.z, h0 = blockIdx.x * 32, l0 = blockIdx.y * 32;
    t[threadIdx.y][threadIdx.x] =
        yT[(b * H_ + h0 + threadIdx.y) * L_ + l0 + threadIdx.x];
    __syncthreads();
    Y[(b * L_ + l0 + threadIdx.y) * H_ + h0 + threadIdx.x] =
        t[threadIdx.x][threadIdx.y];
}

// ---------------------------------------------------------------------------
// K4a: W [K=1024, 2048] f32 -> Wt [2048, K] bf16 (GEMM B, k-contiguous rows)
// ---------------------------------------------------------------------------
__global__ __launch_bounds__(1024) void transpose_w(
        const float* __restrict__ W, __hip_bfloat16* __restrict__ Wt) {
    __shared__ float t[32][33];
    int n0 = blockIdx.x * 32, k0 = blockIdx.y * 32;
    t[threadIdx.y][threadIdx.x] = W[(k0 + threadIdx.y) * 2048 + n0 + threadIdx.x];
    __syncthreads();
    Wt[(n0 + threadIdx.y) * H_ + k0 + threadIdx.x] =
        __float2bfloat16(t[threadIdx.x][threadIdx.y]);
}

// ---------------------------------------------------------------------------
// K4: Z = Y @ Wt^T (+b), fused GLU epilogue: out = za * sigmoid(zg)
// (unchanged from R1)
// ---------------------------------------------------------------------------
__global__ __launch_bounds__(256, 2) void gemm_glu(
        const __hip_bfloat16* __restrict__ Y, const __hip_bfloat16* __restrict__ Wt,
        const float* __restrict__ bv, float* __restrict__ out) {
    __shared__ char lds[32768];
    char* sA  = lds;             // [128 rows][8 chunks * 16B] = 16 KiB
    char* sBa = lds + 16384;     // [64][128B] = 8 KiB
    char* sBg = lds + 24576;     // [64][128B] = 8 KiB

    int tid = threadIdx.x, wv = tid >> 6, lane = tid & 63;
    int mb = (blockIdx.x & 127) * 128;       // m-block
    int h0 = (blockIdx.x >> 7) * 64;         // h-block
    int r8 = lane >> 3, c8 = lane & 7, csrc = c8 ^ r8;
    int wm = (wv >> 1) * 64, wn = (wv & 1) * 32;
    int lm = lane & 15, q = lane >> 4;

    const char* Yb = (const char*)Y;
    const char* Wb = (const char*)Wt;

    f32x4 accA[4][2], accG[4][2];
#pragma unroll
    for (int i = 0; i < 4; ++i)
#pragma unroll
        for (int j = 0; j < 2; ++j) {
            accA[i][j] = (f32x4){0.f, 0.f, 0.f, 0.f};
            accG[i][j] = (f32x4){0.f, 0.f, 0.f, 0.f};
        }

    for (int kt = 0; kt < 16; ++kt) {
        int k0b = kt * 128;
        __syncthreads();
#pragma unroll
        for (int j = 0; j < 4; ++j) {
            int i = wv * 4 + j;
            gll16(Yb + (size_t)(mb + i * 8 + r8) * 2048 + k0b + csrc * 16,
                  sA + i * 1024);
        }
#pragma unroll
        for (int j = 0; j < 2; ++j) {
            int i = wv * 2 + j;
            int n = h0 + i * 8 + r8;
            gll16(Wb + (size_t)n * 2048 + k0b + csrc * 16, sBa + i * 1024);
            gll16(Wb + (size_t)(n + 1024) * 2048 + k0b + csrc * 16, sBg + i * 1024);
        }
        __syncthreads();
#pragma unroll
        for (int kk = 0; kk < 2; ++kk) {
            int clog = kk * 4 + q;
            bf16x8 af[4], ba[2], bg[2];
#pragma unroll
            for (int mt = 0; mt < 4; ++mt) {
                int m = wm + mt * 16 + lm;
                af[mt] = *(const bf16x8*)(sA + m * 128 + ((clog ^ (m & 7)) * 16));
            }
#pragma unroll
            for (int nt = 0; nt < 2; ++nt) {
                int n = wn + nt * 16 + lm;
                int cph = (clog ^ (n & 7)) * 16;
                ba[nt] = *(const bf16x8*)(sBa + n * 128 + cph);
                bg[nt] = *(const bf16x8*)(sBg + n * 128 + cph);
            }
#pragma unroll
            for (int mt = 0; mt < 4; ++mt)
#pragma unroll
                for (int nt = 0; nt < 2; ++nt) {
                    accA[mt][nt] = __builtin_amdgcn_mfma_f32_16x16x32_bf16(
                        af[mt], ba[nt], accA[mt][nt], 0, 0, 0);
                    accG[mt][nt] = __builtin_amdgcn_mfma_f32_16x16x32_bf16(
                        af[mt], bg[nt], accG[mt][nt], 0, 0, 0);
                }
        }
    }
#pragma unroll
    for (int mt = 0; mt < 4; ++mt)
#pragma unroll
        for (int nt = 0; nt < 2; ++nt) {
            int hc = h0 + wn + nt * 16 + lm;
            float bba = bv[hc], bbg = bv[hc + 1024];
#pragma unroll
            for (int r = 0; r < 4; ++r) {
                int m = mb + wm + mt * 16 + q * 4 + r;
                float za = accA[mt][nt][r] + bba;
                float zg = accG[mt][nt][r] + bbg;
                out[(size_t)m * H_ + hc] = za / (1.0f + expf(-zg));
            }
        }
}

// ---------------------------------------------------------------------------
extern "C" void kernel_launch(void* const* d_in, const int* in_sizes, int n_in,
                              void* d_out, int out_size, void* d_ws, size_t ws_size,
                              hipStream_t stream) {
    const float* x      = (const float*)d_in[0];
    const float* log_dt = (const float*)d_in[1];
    const float* Arl    = (const float*)d_in[2];
    const float* Aim    = (const float*)d_in[3];
    const float* Cr     = (const float*)d_in[4];
    const float* Ci     = (const float*)d_in[5];
    const float* Dv     = (const float*)d_in[6];
    const float* W      = (const float*)d_in[7];
    const float* bv     = (const float*)d_in[8];
    float* out = (float*)d_out;

    char* ws = (char*)d_ws;
    // layout:
    //   [0,   64M) xT f32           (reused as Ybf bf16 after chunk_scan)
    //   [64M, 96M) yTa bf16
    //   [96M, ...) Bt 24M | Qt 16M | wT 0.5M | Wt 4M     (peak ~141 MB)
    float*           xT  = (float*)ws;
    __hip_bfloat16*  Ybf = (__hip_bfloat16*)ws;
    __hip_bfloat16*  yTa = (__hip_bfloat16*)(ws + (64u << 20));
    char*            Btg = ws + (96u << 20);
    char*            Qtg = Btg + (size_t)H_ * 192 * 64 * 2;          // +24M
    float2*          wTg = (float2*)(Qtg + (size_t)H_ * 64 * 128 * 2);
    __hip_bfloat16*  Wt  = (__hip_bfloat16*)((char*)wTg + (size_t)H_ * N_ * 8);

    dim3 tb(32, 32);
    build_tables<<<1024, 64, 0, stream>>>(log_dt, Arl, Aim, Cr, Ci,
                                          (__hip_bfloat16*)Btg,
                                          (__hip_bfloat16*)Qtg, wTg);
    transpose_x<<<dim3(32, 32, 16), tb, 0, stream>>>(x, xT);
    transpose_w<<<dim3(64, 32), tb, 0, stream>>>(W, Wt);
    chunk_scan<<<2048, 256, 0, stream>>>(xT, Btg, Qtg, wTg, Dv, yTa);
    transpose_y<<<dim3(32, 32, 16), tb, 0, stream>>>(
        (const unsigned short*)yTa, (unsigned short*)Ybf);
    gemm_glu<<<2048, 256, 0, stream>>>(Ybf, Wt, bv, out);
}

// Round 3
// 347.386 us; speedup vs baseline: 1.8227x; 1.1117x over previous
//
#include <hip/hip_runtime.h>
#include <hip/hip_bf16.h>

// Problem constants
#define B_ 16
#define L_ 1024
#define H_ 1024
#define N_ 64
// M = B*L = 16384, K = H = 1024, output cols = 2H = 2048 (a|g pairs)
// Chunked SSM: T=64 chunk, 16 chunks/seq.

typedef __bf16 bf16x8 __attribute__((ext_vector_type(8)));
typedef float  f32x4  __attribute__((ext_vector_type(4)));

// async global->LDS, 16B per lane; LDS dest is wave-uniform base + lane*16
__device__ __forceinline__ void gll16(const void* g, void* l) {
    __builtin_amdgcn_global_load_lds(
        (const __attribute__((address_space(1))) unsigned int*)g,
        (__attribute__((address_space(3))) unsigned int*)l,
        16, 0, 0);
}

__device__ __forceinline__ float gelu_tanh(float yv) {
    float u = yv + 0.044715f * yv * yv * yv;
    return 0.5f * yv * (1.0f + tanhf(0.7978845608028654f * u));
}

// ---------------------------------------------------------------------------
// K0: per-h tables (rewritten for parallelism + coalesced writes).
//  Bt [H][192][64] bf16: rows 0..63  = Toeplitz k[t-j]; rows 64+2n+e =
//                        Re/Im(w_n^{63-j})
//  Qt [H][64][128] bf16: Qt[t][2n] = Re(2c w^{t+1}), [2n+1] = -Im(...)
//  wT [H][N] float2: w^64
// Block = one h, 256 threads. w^j computed directly as exp(j dr) cis(j di).
// ---------------------------------------------------------------------------
__global__ __launch_bounds__(256) void build_tables(
        const float* __restrict__ log_dt, const float* __restrict__ Arl,
        const float* __restrict__ Aim, const float* __restrict__ Cr,
        const float* __restrict__ Ci,
        __hip_bfloat16* __restrict__ Bt, __hip_bfloat16* __restrict__ Qt,
        float2* __restrict__ wT) {
    __shared__ float Rw[64][67], Iw[64][67];   // stride 67: odd -> 2-way banks
    __shared__ float drs[64], dis[64], c2rs[64], c2is[64];
    __shared__ float kp[4][64], kv[64];
    int h = blockIdx.x, t = threadIdx.x;

    if (t < 64) {                              // per-n parameters
        int n = t, i = h * 64 + n;
        float dt = expf(log_dt[h]);
        float ar = -expf(Arl[i]), ai = Aim[i];
        float dr = dt * ar, di = dt * ai;
        drs[n] = dr; dis[n] = di;
        float e = expf(dr);
        float wr = e * cosf(di), wi = e * sinf(di);
        float em1r = wr - 1.0f, em1i = wi;     // exp(dtA)-1
        float Crv = Cr[i], Civ = Ci[i];
        float tr = Crv * em1r - Civ * em1i;
        float ti = Crv * em1i + Civ * em1r;
        float inv = 1.0f / (ar * ar + ai * ai);
        c2rs[n] = 2.0f * (tr * ar + ti * ai) * inv;
        c2is[n] = 2.0f * (ti * ar - tr * ai) * inv;
    }
    __syncthreads();
    // all powers w^j, j in [0,64], parallel over (n,j)
#pragma unroll
    for (int it = 0; it < 17; ++it) {
        int idx = it * 256 + t;
        if (idx < 4160) {
            int n = idx & 63, j = idx >> 6;
            float jf = (float)j;
            float er = expf(jf * drs[n]);
            float ph = jf * dis[n];
            float wr = er * cosf(ph), wi = er * sinf(ph);
            Rw[n][j] = wr; Iw[n][j] = wi;
            if (j == 64) wT[h * 64 + n] = make_float2(wr, wi);
        }
    }
    __syncthreads();
    // k[j] = sum_n Re(c2 w^j): 4 partial sums of 16 n each
    {
        int j = t & 63, part = t >> 6;
        float s = 0.0f;
        for (int nn = part * 16; nn < part * 16 + 16; ++nn)
            s += c2rs[nn] * Rw[nn][j] - c2is[nn] * Iw[nn][j];
        kp[part][j] = s;
    }
    __syncthreads();
    if (t < 64) kv[t] = kp[0][t] + kp[1][t] + kp[2][t] + kp[3][t];
    __syncthreads();
    // Toeplitz rows (4096 elems, coalesced)
#pragma unroll
    for (int it = 0; it < 16; ++it) {
        int idx = it * 256 + t, row = idx >> 6, col = idx & 63;
        int d = row - col;
        float v = (d >= 0) ? kv[d] : 0.0f;
        Bt[(size_t)(h * 192 + row) * 64 + col] = __float2bfloat16(v);
    }
    // Vandermonde rows (8192 elems, coalesced)
#pragma unroll
    for (int it = 0; it < 32; ++it) {
        int idx = it * 256 + t, rr = idx >> 6, j = idx & 63;
        int n = rr >> 1;
        float v = (rr & 1) ? Iw[n][63 - j] : Rw[n][63 - j];
        Bt[(size_t)(h * 192 + 64 + rr) * 64 + j] = __float2bfloat16(v);
    }
    // Qt (8192 elems, coalesced)
#pragma unroll
    for (int it = 0; it < 32; ++it) {
        int idx = it * 256 + t, trow = idx >> 7, colc = idx & 127;
        int n = colc >> 1, e = colc & 1;
        float wr = Rw[n][trow + 1], wi = Iw[n][trow + 1];
        float cR = c2rs[n] * wr - c2is[n] * wi;
        float cI = c2rs[n] * wi + c2is[n] * wr;
        Qt[(size_t)(h * 64 + trow) * 128 + colc] =
            __float2bfloat16(e ? -cI : cR);
    }
}

// ---------------------------------------------------------------------------
// K1: x [B,L,H] f32 -> xT [B*H, L] f32
// ---------------------------------------------------------------------------
__global__ __launch_bounds__(1024) void transpose_x(
        const float* __restrict__ x, float* __restrict__ xT) {
    __shared__ float t[32][33];
    int b = blockIdx.z, h0 = blockIdx.x * 32, l0 = blockIdx.y * 32;
    t[threadIdx.y][threadIdx.x] =
        x[b * (L_ * H_) + (l0 + threadIdx.y) * H_ + h0 + threadIdx.x];
    __syncthreads();
    xT[(b * H_ + h0 + threadIdx.y) * L_ + l0 + threadIdx.x] =
        t[threadIdx.x][threadIdx.y];
}

// ---------------------------------------------------------------------------
// K2: fused chunked SSM (restructured: M=64 rows = 4 batches, 48K LDS,
// 3 blocks/CU). Math identical to R2's passing kernel.
// LDS: phase1 sX[64][128B]@0 8K, sB[192][128B]@8K 24K, sQ[64][256B]@32K 16K;
//      phase2 sS f32[64 rows][512B]@0 32K (overlays sX+sB; sQ disjoint).
// ---------------------------------------------------------------------------
__global__ __launch_bounds__(256, 3) void chunk_scan(
        const float* __restrict__ xT, const char* __restrict__ Btg,
        const char* __restrict__ Qtg, const float2* __restrict__ wTg,
        const float* __restrict__ Dv, __hip_bfloat16* __restrict__ yTa) {
    __shared__ char lds[49152];
    char* sX = lds;              // [64][128B]
    char* sB = lds + 8192;       // [192][128B]
    char* sS = lds;              // [64 rows][512B] f32, post-GEMM1 overlay
    char* sQ = lds + 32768;      // [64][256B]

    int tid = threadIdx.x, wv = tid >> 6, lane = tid & 63;
    int lm = lane & 15, q = lane >> 4, r8 = lane >> 3, c8 = lane & 7;
    int h  = blockIdx.x >> 2;
    int b0 = (blockIdx.x & 3) * 4;

    // ---- stage sB: 24 wave-loads of 8 rows x 128B ----
    int csrc = c8 ^ r8;
#pragma unroll
    for (int j = 0; j < 6; ++j) {
        int i = wv * 6 + j;
        gll16(Btg + ((size_t)(h * 192 + i * 8 + r8)) * 128 + csrc * 16,
              sB + i * 1024);
    }
    // ---- stage sQ: 16 wave-loads of 4 rows x 256B (region never aliased) --
    {
        int r4 = lane >> 4, c16 = lane & 15;
#pragma unroll
        for (int j = 0; j < 4; ++j) {
            int i = wv * 4 + j;
            gll16(Qtg + (size_t)(h * 64 + i * 4 + r4) * 256 + (c16 ^ r4) * 16,
                  sQ + i * 1024);
        }
    }
    // ---- stage sX: 64 rows x 128B; 4 threads/row, 2 chunks each ----
    {
        int row = tid >> 2, quad = tid & 3;
        int seq = (b0 + (row >> 4)) * H_ + h;
        const float* gp = xT + (size_t)seq * L_ + (row & 15) * 64;
#pragma unroll
        for (int j = 0; j < 2; ++j) {
            int ch = quad * 2 + j;
            float4 v0 = *(const float4*)(gp + ch * 8);
            float4 v1 = *(const float4*)(gp + ch * 8 + 4);
            bf16x8 pk;
            pk[0] = (__bf16)v0.x; pk[1] = (__bf16)v0.y;
            pk[2] = (__bf16)v0.z; pk[3] = (__bf16)v0.w;
            pk[4] = (__bf16)v1.x; pk[5] = (__bf16)v1.y;
            pk[6] = (__bf16)v1.z; pk[7] = (__bf16)v1.w;
            *(bf16x8*)(sX + row * 128 + ((ch ^ (row & 7)) * 16)) = pk;
        }
    }
    __syncthreads();

    // ---- GEMM1: wave rows wv*16+lm, N=192 (12 tiles), K=64 ----
    f32x4 acc[12];
#pragma unroll
    for (int nt = 0; nt < 12; ++nt) acc[nt] = (f32x4){0.f, 0.f, 0.f, 0.f};
#pragma unroll
    for (int kk = 0; kk < 2; ++kk) {
        int clog = kk * 4 + q;
        int m = wv * 16 + lm;
        bf16x8 af = *(const bf16x8*)(sX + m * 128 + ((clog ^ (m & 7)) * 16));
#pragma unroll
        for (int nt = 0; nt < 12; ++nt) {
            int nrow = nt * 16 + lm;
            bf16x8 bf = *(const bf16x8*)(sB + nrow * 128 + ((clog ^ (nrow & 7)) * 16));
            acc[nt] = __builtin_amdgcn_mfma_f32_16x16x32_bf16(
                af, bf, acc[nt], 0, 0, 0);
        }
    }
    __syncthreads();   // everyone done with sX/sB -> sS overlay is safe

    // ---- write Sloc (nt 4..11 -> ri 0..127) into sS f32 swizzled ----
#pragma unroll
    for (int nt = 4; nt < 12; ++nt) {
        int ri = (nt - 4) * 16 + lm;
#pragma unroll
        for (int r = 0; r < 4; ++r) {
            int row = wv * 16 + q * 4 + r;
            *(float*)(sS + row * 512 + (((ri >> 2) ^ (row & 7)) * 16)
                      + (ri & 3) * 4) = acc[nt][r];
        }
    }
    __syncthreads();

    // ---- serial chunk scan: one chain per thread (n = tid&63, bp = wv) ----
    {
        int n = tid & 63, bp = tid >> 6;
        float2 wt = wTg[h * 64 + n];             // w^64
        float sr = 0.0f, si = 0.0f;
#pragma unroll 1
        for (int c = 0; c < 16; ++c) {
            int row = bp * 16 + c;
            char* p = sS + row * 512 + (((n >> 1) ^ (row & 7)) * 16)
                      + (n & 1) * 8;
            float2 loc = *(float2*)p;
            *(float2*)p = make_float2(sr, si);   // S_in before update
            float nr2 = wt.x * sr - wt.y * si + loc.x;
            float ni2 = wt.x * si + wt.y * sr + loc.y;
            sr = nr2; si = ni2;
        }
    }
    __syncthreads();

    // ---- GEMM2: y += S_in[64 x 128] * Qt^T, K=128 (4 k-steps) ----
#pragma unroll
    for (int ks = 0; ks < 4; ++ks) {
        int row = wv * 16 + lm;
        int cf0 = ks * 8 + q * 2;
        f32x4 a0 = *(const f32x4*)(sS + row * 512 + ((cf0 ^ (row & 7)) * 16));
        f32x4 a1 = *(const f32x4*)(sS + row * 512 + (((cf0 + 1) ^ (row & 7)) * 16));
        bf16x8 af;
        af[0] = (__bf16)a0[0]; af[1] = (__bf16)a0[1];
        af[2] = (__bf16)a0[2]; af[3] = (__bf16)a0[3];
        af[4] = (__bf16)a1[0]; af[5] = (__bf16)a1[1];
        af[6] = (__bf16)a1[2]; af[7] = (__bf16)a1[3];
#pragma unroll
        for (int nt = 0; nt < 4; ++nt) {
            int trow = nt * 16 + lm;
            int clog = ks * 4 + q;
            bf16x8 bq = *(const bf16x8*)(sQ + trow * 256 + ((clog ^ (trow & 3)) * 16));
            acc[nt] = __builtin_amdgcn_mfma_f32_16x16x32_bf16(
                af, bq, acc[nt], 0, 0, 0);
        }
    }

    // ---- epilogue: D-skip (f32 x) + GELU -> yTa ----
    float Dh = Dv[h];
#pragma unroll
    for (int nt = 0; nt < 4; ++nt)
#pragma unroll
        for (int r = 0; r < 4; ++r) {
            int row = wv * 16 + q * 4 + r;
            int seq = (b0 + (row >> 4)) * H_ + h;
            int l   = (row & 15) * 64 + nt * 16 + lm;
            float yv = acc[nt][r] + xT[(size_t)seq * L_ + l] * Dh;
            yTa[(size_t)seq * L_ + l] = __float2bfloat16(gelu_tanh(yv));
        }
}

// ---------------------------------------------------------------------------
// K3: yT_act [B*H, L] bf16 -> Y [B*L, H] bf16
// ---------------------------------------------------------------------------
__global__ __launch_bounds__(1024) void transpose_y(
        const unsigned short* __restrict__ yT, unsigned short* __restrict__ Y) {
    __shared__ unsigned short t[32][33];
    int b = blockIdx.z, h0 = blockIdx.x * 32, l0 = blockIdx.y * 32;
    t[threadIdx.y][threadIdx.x] =
        yT[(b * H_ + h0 + threadIdx.y) * L_ + l0 + threadIdx.x];
    __syncthreads();
    Y[(b * L_ + l0 + threadIdx.y) * H_ + h0 + threadIdx.x] =
        t[threadIdx.x][threadIdx.y];
}

// ---------------------------------------------------------------------------
// K4a: W [K=1024, 2048] f32 -> Wt [2048, K] bf16
// ---------------------------------------------------------------------------
__global__ __launch_bounds__(1024) void transpose_w(
        const float* __restrict__ W, __hip_bfloat16* __restrict__ Wt) {
    __shared__ float t[32][33];
    int n0 = blockIdx.x * 32, k0 = blockIdx.y * 32;
    t[threadIdx.y][threadIdx.x] = W[(k0 + threadIdx.y) * 2048 + n0 + threadIdx.x];
    __syncthreads();
    Wt[(n0 + threadIdx.y) * H_ + k0 + threadIdx.x] =
        __float2bfloat16(t[threadIdx.x][threadIdx.y]);
}

// ---------------------------------------------------------------------------
// K4: Z = Y @ Wt^T (+b), fused GLU epilogue (unchanged from R2)
// ---------------------------------------------------------------------------
__global__ __launch_bounds__(256, 2) void gemm_glu(
        const __hip_bfloat16* __restrict__ Y, const __hip_bfloat16* __restrict__ Wt,
        const float* __restrict__ bv, float* __restrict__ out) {
    __shared__ char lds[32768];
    char* sA  = lds;             // [128 rows][8 chunks * 16B] = 16 KiB
    char* sBa = lds + 16384;     // [64][128B] = 8 KiB
    char* sBg = lds + 24576;     // [64][128B] = 8 KiB

    int tid = threadIdx.x, wv = tid >> 6, lane = tid & 63;
    int mb = (blockIdx.x & 127) * 128;
    int h0 = (blockIdx.x >> 7) * 64;
    int r8 = lane >> 3, c8 = lane & 7, csrc = c8 ^ r8;
    int wm = (wv >> 1) * 64, wn = (wv & 1) * 32;
    int lm = lane & 15, q = lane >> 4;

    const char* Yb = (const char*)Y;
    const char* Wb = (const char*)Wt;

    f32x4 accA[4][2], accG[4][2];
#pragma unroll
    for (int i = 0; i < 4; ++i)
#pragma unroll
        for (int j = 0; j < 2; ++j) {
            accA[i][j] = (f32x4){0.f, 0.f, 0.f, 0.f};
            accG[i][j] = (f32x4){0.f, 0.f, 0.f, 0.f};
        }

    for (int kt = 0; kt < 16; ++kt) {
        int k0b = kt * 128;
        __syncthreads();
#pragma unroll
        for (int j = 0; j < 4; ++j) {
            int i = wv * 4 + j;
            gll16(Yb + (size_t)(mb + i * 8 + r8) * 2048 + k0b + csrc * 16,
                  sA + i * 1024);
        }
#pragma unroll
        for (int j = 0; j < 2; ++j) {
            int i = wv * 2 + j;
            int n = h0 + i * 8 + r8;
            gll16(Wb + (size_t)n * 2048 + k0b + csrc * 16, sBa + i * 1024);
            gll16(Wb + (size_t)(n + 1024) * 2048 + k0b + csrc * 16, sBg + i * 1024);
        }
        __syncthreads();
#pragma unroll
        for (int kk = 0; kk < 2; ++kk) {
            int clog = kk * 4 + q;
            bf16x8 af[4], ba[2], bg[2];
#pragma unroll
            for (int mt = 0; mt < 4; ++mt) {
                int m = wm + mt * 16 + lm;
                af[mt] = *(const bf16x8*)(sA + m * 128 + ((clog ^ (m & 7)) * 16));
            }
#pragma unroll
            for (int nt = 0; nt < 2; ++nt) {
                int n = wn + nt * 16 + lm;
                int cph = (clog ^ (n & 7)) * 16;
                ba[nt] = *(const bf16x8*)(sBa + n * 128 + cph);
                bg[nt] = *(const bf16x8*)(sBg + n * 128 + cph);
            }
#pragma unroll
            for (int mt = 0; mt < 4; ++mt)
#pragma unroll
                for (int nt = 0; nt < 2; ++nt) {
                    accA[mt][nt] = __builtin_amdgcn_mfma_f32_16x16x32_bf16(
                        af[mt], ba[nt], accA[mt][nt], 0, 0, 0);
                    accG[mt][nt] = __builtin_amdgcn_mfma_f32_16x16x32_bf16(
                        af[mt], bg[nt], accG[mt][nt], 0, 0, 0);
                }
        }
    }
#pragma unroll
    for (int mt = 0; mt < 4; ++mt)
#pragma unroll
        for (int nt = 0; nt < 2; ++nt) {
            int hc = h0 + wn + nt * 16 + lm;
            float bba = bv[hc], bbg = bv[hc + 1024];
#pragma unroll
            for (int r = 0; r < 4; ++r) {
                int m = mb + wm + mt * 16 + q * 4 + r;
                float za = accA[mt][nt][r] + bba;
                float zg = accG[mt][nt][r] + bbg;
                out[(size_t)m * H_ + hc] = za / (1.0f + expf(-zg));
            }
        }
}

// ---------------------------------------------------------------------------
extern "C" void kernel_launch(void* const* d_in, const int* in_sizes, int n_in,
                              void* d_out, int out_size, void* d_ws, size_t ws_size,
                              hipStream_t stream) {
    const float* x      = (const float*)d_in[0];
    const float* log_dt = (const float*)d_in[1];
    const float* Arl    = (const float*)d_in[2];
    const float* Aim    = (const float*)d_in[3];
    const float* Cr     = (const float*)d_in[4];
    const float* Ci     = (const float*)d_in[5];
    const float* Dv     = (const float*)d_in[6];
    const float* W      = (const float*)d_in[7];
    const float* bv     = (const float*)d_in[8];
    float* out = (float*)d_out;

    char* ws = (char*)d_ws;
    // layout:
    //   [0,   64M) xT f32           (reused as Ybf bf16 after chunk_scan)
    //   [64M, 96M) yTa bf16
    //   [96M, ...) Bt 24M | Qt 16M | wT 0.5M | Wt 4M     (peak ~141 MB)
    float*           xT  = (float*)ws;
    __hip_bfloat16*  Ybf = (__hip_bfloat16*)ws;
    __hip_bfloat16*  yTa = (__hip_bfloat16*)(ws + (64u << 20));
    char*            Btg = ws + (96u << 20);
    char*            Qtg = Btg + (size_t)H_ * 192 * 64 * 2;          // +24M
    float2*          wTg = (float2*)(Qtg + (size_t)H_ * 64 * 128 * 2);
    __hip_bfloat16*  Wt  = (__hip_bfloat16*)((char*)wTg + (size_t)H_ * N_ * 8);

    dim3 tb(32, 32);
    build_tables<<<1024, 256, 0, stream>>>(log_dt, Arl, Aim, Cr, Ci,
                                           (__hip_bfloat16*)Btg,
                                           (__hip_bfloat16*)Qtg, wTg);
    transpose_x<<<dim3(32, 32, 16), tb, 0, stream>>>(x, xT);
    transpose_w<<<dim3(64, 32), tb, 0, stream>>>(W, Wt);
    chunk_scan<<<4096, 256, 0, stream>>>(xT, Btg, Qtg, wTg, Dv, yTa);
    transpose_y<<<dim3(32, 32, 16), tb, 0, stream>>>(
        (const unsigned short*)yTa, (unsigned short*)Ybf);
    gemm_glu<<<2048, 256, 0, stream>>>(Ybf, Wt, bv, out);
}

// Round 4
// 308.800 us; speedup vs baseline: 2.0505x; 1.1250x over previous
//
#include <hip/hip_runtime.h>
#include <hip/hip_bf16.h>

// Problem constants
#define B_ 16
#define L_ 1024
#define H_ 1024
#define N_ 64
// M = B*L = 16384, K = H = 1024, output cols = 2H = 2048 (a|g pairs)
// Chunked SSM: T=64 chunk, 16 chunks/seq.

typedef __bf16 bf16x8 __attribute__((ext_vector_type(8)));
typedef float  f32x4  __attribute__((ext_vector_type(4)));
typedef unsigned short u16x8 __attribute__((ext_vector_type(8)));

// async global->LDS, 16B per lane; LDS dest is wave-uniform base + lane*16
__device__ __forceinline__ void gll16(const void* g, void* l) {
    __builtin_amdgcn_global_load_lds(
        (const __attribute__((address_space(1))) unsigned int*)g,
        (__attribute__((address_space(3))) unsigned int*)l,
        16, 0, 0);
}

__device__ __forceinline__ float gelu_tanh(float yv) {
    float u = yv + 0.044715f * yv * yv * yv;
    return 0.5f * yv * (1.0f + tanhf(0.7978845608028654f * u));
}

// ---------------------------------------------------------------------------
// K0 "prep": one kernel, 2176 blocks x 256 threads.
//  [0,1024):    x [B,L,H] f32 -> xTb [B*H, L] bf16   (LDS-free transpose:
//               scattered 16B float4 reads (L1-resident), coalesced 128B
//               row writes)
//  [1024,1152): W [1024,2048] f32 -> Wt [2048,1024] bf16 (same scheme)
//  [1152,2176): build_tables (Bt/Qt/wT), one h per block
// ---------------------------------------------------------------------------
__global__ __launch_bounds__(256) void prep(
        const float* __restrict__ x, const float* __restrict__ log_dt,
        const float* __restrict__ Arl, const float* __restrict__ Aim,
        const float* __restrict__ Cr, const float* __restrict__ Ci,
        const float* __restrict__ W,
        __hip_bfloat16* __restrict__ xTb, __hip_bfloat16* __restrict__ Bt,
        __hip_bfloat16* __restrict__ Qt, float2* __restrict__ wT,
        __hip_bfloat16* __restrict__ Wt) {
    __shared__ char sm[36608];
    int idx = blockIdx.x, t = threadIdx.x;
    int wv = t >> 6, lane = t & 63;

    if (idx < 1024) {
        // ---- x transpose: block covers b, l-tile 64, h-range 256 ----
        int b = idx >> 6, lt = (idx >> 2) & 15, ht = idx & 3;
        int l0 = lt * 64;
        int hb0 = ht * 256 + wv * 64;
        const float* src = x + ((size_t)b * L_ + l0 + lane) * H_;
#pragma unroll
        for (int j = 0; j < 16; ++j) {
            float4 v = *(const float4*)(src + hb0 + j * 4);
            int hh = hb0 + j * 4;
            __hip_bfloat16* dp = xTb + ((size_t)b * H_ + hh) * L_ + l0 + lane;
            dp[0]        = __float2bfloat16(v.x);
            dp[L_]       = __float2bfloat16(v.y);
            dp[2 * L_]   = __float2bfloat16(v.z);
            dp[3 * L_]   = __float2bfloat16(v.w);
        }
        return;
    }
    if (idx < 1152) {
        // ---- W transpose: block covers k-tile 64 (lanes), n-range 256 ----
        int id2 = idx - 1024;
        int kt = id2 >> 3, ntile = id2 & 7;
        int k0 = kt * 64;
        int nb0 = ntile * 256 + wv * 64;
        const float* src = W + ((size_t)(k0 + lane)) * 2048;
#pragma unroll
        for (int j = 0; j < 16; ++j) {
            float4 v = *(const float4*)(src + nb0 + j * 4);
            int nn = nb0 + j * 4;
            __hip_bfloat16* dp = Wt + (size_t)nn * H_ + k0 + lane;
            dp[0]      = __float2bfloat16(v.x);
            dp[H_]     = __float2bfloat16(v.y);
            dp[2 * H_] = __float2bfloat16(v.z);
            dp[3 * H_] = __float2bfloat16(v.w);
        }
        return;
    }
    // ---- build_tables: h = idx - 1152 ----
    {
        float (*Rw)[67]  = (float(*)[67])sm;             // 17152
        float (*Iw)[67]  = (float(*)[67])(sm + 17152);   // -> 34304
        float* drs  = (float*)(sm + 34304);
        float* dis  = (float*)(sm + 34560);
        float* c2rs = (float*)(sm + 34816);
        float* c2is = (float*)(sm + 35072);
        float (*kp)[64] = (float(*)[64])(sm + 35328);    // 1024 -> 36352
        float* kv   = (float*)(sm + 36352);
        int h = idx - 1152;

        if (t < 64) {
            int n = t, i = h * 64 + n;
            float dt = expf(log_dt[h]);
            float ar = -expf(Arl[i]), ai = Aim[i];
            float dr = dt * ar, di = dt * ai;
            drs[n] = dr; dis[n] = di;
            float e = expf(dr);
            float wr = e * cosf(di), wi = e * sinf(di);
            float em1r = wr - 1.0f, em1i = wi;
            float Crv = Cr[i], Civ = Ci[i];
            float tr = Crv * em1r - Civ * em1i;
            float ti = Crv * em1i + Civ * em1r;
            float inv = 1.0f / (ar * ar + ai * ai);
            c2rs[n] = 2.0f * (tr * ar + ti * ai) * inv;
            c2is[n] = 2.0f * (ti * ar - tr * ai) * inv;
        }
        __syncthreads();
#pragma unroll
        for (int it = 0; it < 17; ++it) {
            int id3 = it * 256 + t;
            if (id3 < 4160) {
                int n = id3 & 63, j = id3 >> 6;
                float jf = (float)j;
                float er = expf(jf * drs[n]);
                float ph = jf * dis[n];
                float wr = er * cosf(ph), wi = er * sinf(ph);
                Rw[n][j] = wr; Iw[n][j] = wi;
                if (j == 64) wT[h * 64 + n] = make_float2(wr, wi);
            }
        }
        __syncthreads();
        {
            int j = t & 63, part = t >> 6;
            float s = 0.0f;
            for (int nn = part * 16; nn < part * 16 + 16; ++nn)
                s += c2rs[nn] * Rw[nn][j] - c2is[nn] * Iw[nn][j];
            kp[part][j] = s;
        }
        __syncthreads();
        if (t < 64) kv[t] = kp[0][t] + kp[1][t] + kp[2][t] + kp[3][t];
        __syncthreads();
#pragma unroll
        for (int it = 0; it < 16; ++it) {
            int id3 = it * 256 + t, row = id3 >> 6, col = id3 & 63;
            int d = row - col;
            float v = (d >= 0) ? kv[d] : 0.0f;
            Bt[(size_t)(h * 192 + row) * 64 + col] = __float2bfloat16(v);
        }
#pragma unroll
        for (int it = 0; it < 32; ++it) {
            int id3 = it * 256 + t, rr = id3 >> 6, j = id3 & 63;
            int n = rr >> 1;
            float v = (rr & 1) ? Iw[n][63 - j] : Rw[n][63 - j];
            Bt[(size_t)(h * 192 + 64 + rr) * 64 + j] = __float2bfloat16(v);
        }
#pragma unroll
        for (int it = 0; it < 32; ++it) {
            int id3 = it * 256 + t, trow = id3 >> 7, colc = id3 & 127;
            int n = colc >> 1, e = colc & 1;
            float wr = Rw[n][trow + 1], wi = Iw[n][trow + 1];
            float cR = c2rs[n] * wr - c2is[n] * wi;
            float cI = c2rs[n] * wi + c2is[n] * wr;
            Qt[(size_t)(h * 64 + trow) * 128 + colc] =
                __float2bfloat16(e ? -cI : cR);
        }
    }
}

// ---------------------------------------------------------------------------
// K2: fused chunked SSM (M=64 rows = 4 batches, 48K LDS, 3 blocks/CU).
// sX now staged via gll16 from bf16 xTb; epilogue D-skip reads bf16 x.
// XCD swizzle: the 4 blocks sharing h get blockIdx ≡ same (mod 8).
// LDS: phase1 sX[64][128B]@0 8K, sB[192][128B]@8K 24K, sQ[64][256B]@32K 16K;
//      phase2 sS f32[64 rows][512B]@0 32K (overlays sX+sB; sQ disjoint).
// ---------------------------------------------------------------------------
__global__ __launch_bounds__(256, 3) void chunk_scan(
        const __hip_bfloat16* __restrict__ xTb, const char* __restrict__ Btg,
        const char* __restrict__ Qtg, const float2* __restrict__ wTg,
        const float* __restrict__ Dv, __hip_bfloat16* __restrict__ yTa) {
    __shared__ char lds[49152];
    char* sX = lds;              // [64][128B]
    char* sB = lds + 8192;       // [192][128B]
    char* sS = lds;              // [64 rows][512B] f32, post-GEMM1 overlay
    char* sQ = lds + 32768;      // [64][256B]

    int tid = threadIdx.x, wv = tid >> 6, lane = tid & 63;
    int lm = lane & 15, q = lane >> 4, r8 = lane >> 3, c8 = lane & 7;
    // XCD-aware decode: h = (idx>>5)*8 + (idx&7); member m = (idx>>3)&3
    int idx = blockIdx.x;
    int h  = ((idx >> 5) << 3) | (idx & 7);
    int b0 = ((idx >> 3) & 3) * 4;

    int csrc = c8 ^ r8;
    // ---- stage sB: 24 wave-loads of 8 rows x 128B ----
#pragma unroll
    for (int j = 0; j < 6; ++j) {
        int i = wv * 6 + j;
        gll16(Btg + ((size_t)(h * 192 + i * 8 + r8)) * 128 + csrc * 16,
              sB + i * 1024);
    }
    // ---- stage sQ: 16 wave-loads of 4 rows x 256B ----
    {
        int r4 = lane >> 4, c16 = lane & 15;
#pragma unroll
        for (int j = 0; j < 4; ++j) {
            int i = wv * 4 + j;
            gll16(Qtg + (size_t)(h * 64 + i * 4 + r4) * 256 + (c16 ^ r4) * 16,
                  sQ + i * 1024);
        }
    }
    // ---- stage sX via gll16: 8 groups of 8 rows x 128B, 2 per wave ----
    {
        const char* xb = (const char*)xTb;
#pragma unroll
        for (int j = 0; j < 2; ++j) {
            int i = wv * 2 + j;                      // row group
            int bp = b0 + (i >> 1);                  // batch of this group
            int ch = (i & 1) * 8 + r8;               // chunk index (row&15)
            gll16(xb + ((size_t)(bp * H_ + h)) * 2048 + ch * 128 + csrc * 16,
                  sX + i * 1024);
        }
    }
    __syncthreads();

    // ---- GEMM1: wave rows wv*16+lm, N=192 (12 tiles), K=64 ----
    f32x4 acc[12];
#pragma unroll
    for (int nt = 0; nt < 12; ++nt) acc[nt] = (f32x4){0.f, 0.f, 0.f, 0.f};
#pragma unroll
    for (int kk = 0; kk < 2; ++kk) {
        int clog = kk * 4 + q;
        int m = wv * 16 + lm;
        bf16x8 af = *(const bf16x8*)(sX + m * 128 + ((clog ^ (m & 7)) * 16));
#pragma unroll
        for (int nt = 0; nt < 12; ++nt) {
            int nrow = nt * 16 + lm;
            bf16x8 bf = *(const bf16x8*)(sB + nrow * 128 + ((clog ^ (nrow & 7)) * 16));
            acc[nt] = __builtin_amdgcn_mfma_f32_16x16x32_bf16(
                af, bf, acc[nt], 0, 0, 0);
        }
    }
    __syncthreads();   // everyone done with sX/sB -> sS overlay is safe

    // ---- write Sloc (nt 4..11 -> ri 0..127) into sS f32 swizzled ----
#pragma unroll
    for (int nt = 4; nt < 12; ++nt) {
        int ri = (nt - 4) * 16 + lm;
#pragma unroll
        for (int r = 0; r < 4; ++r) {
            int row = wv * 16 + q * 4 + r;
            *(float*)(sS + row * 512 + (((ri >> 2) ^ (row & 7)) * 16)
                      + (ri & 3) * 4) = acc[nt][r];
        }
    }
    __syncthreads();

    // ---- serial chunk scan: one chain per thread (n = tid&63, bp = wv) ----
    {
        int n = tid & 63, bp = tid >> 6;
        float2 wt = wTg[h * 64 + n];             // w^64
        float sr = 0.0f, si = 0.0f;
#pragma unroll 1
        for (int c = 0; c < 16; ++c) {
            int row = bp * 16 + c;
            char* p = sS + row * 512 + (((n >> 1) ^ (row & 7)) * 16)
                      + (n & 1) * 8;
            float2 loc = *(float2*)p;
            *(float2*)p = make_float2(sr, si);   // S_in before update
            float nr2 = wt.x * sr - wt.y * si + loc.x;
            float ni2 = wt.x * si + wt.y * sr + loc.y;
            sr = nr2; si = ni2;
        }
    }
    __syncthreads();

    // ---- GEMM2: y += S_in[64 x 128] * Qt^T, K=128 (4 k-steps) ----
#pragma unroll
    for (int ks = 0; ks < 4; ++ks) {
        int row = wv * 16 + lm;
        int cf0 = ks * 8 + q * 2;
        f32x4 a0 = *(const f32x4*)(sS + row * 512 + ((cf0 ^ (row & 7)) * 16));
        f32x4 a1 = *(const f32x4*)(sS + row * 512 + (((cf0 + 1) ^ (row & 7)) * 16));
        bf16x8 af;
        af[0] = (__bf16)a0[0]; af[1] = (__bf16)a0[1];
        af[2] = (__bf16)a0[2]; af[3] = (__bf16)a0[3];
        af[4] = (__bf16)a1[0]; af[5] = (__bf16)a1[1];
        af[6] = (__bf16)a1[2]; af[7] = (__bf16)a1[3];
#pragma unroll
        for (int nt = 0; nt < 4; ++nt) {
            int trow = nt * 16 + lm;
            int clog = ks * 4 + q;
            bf16x8 bq = *(const bf16x8*)(sQ + trow * 256 + ((clog ^ (trow & 3)) * 16));
            acc[nt] = __builtin_amdgcn_mfma_f32_16x16x32_bf16(
                af, bq, acc[nt], 0, 0, 0);
        }
    }

    // ---- epilogue: D-skip (bf16 x) + GELU -> yTa ----
    float Dh = Dv[h];
#pragma unroll
    for (int nt = 0; nt < 4; ++nt)
#pragma unroll
        for (int r = 0; r < 4; ++r) {
            int row = wv * 16 + q * 4 + r;
            int seq = (b0 + (row >> 4)) * H_ + h;
            int l   = (row & 15) * 64 + nt * 16 + lm;
            float xv = __bfloat162float(xTb[(size_t)seq * L_ + l]);
            float yv = acc[nt][r] + xv * Dh;
            yTa[(size_t)seq * L_ + l] = __float2bfloat16(gelu_tanh(yv));
        }
}

// ---------------------------------------------------------------------------
// K3: yTa [B*H, L] bf16 -> Y [B*L, H] bf16  (LDS-free: scattered 16B reads
// (L1-resident), coalesced 128B stores). 1024 blocks x 256 thr.
// ---------------------------------------------------------------------------
__global__ __launch_bounds__(256) void transpose_y(
        const unsigned short* __restrict__ yT, unsigned short* __restrict__ Y) {
    int idx = blockIdx.x, t = threadIdx.x;
    int wv = t >> 6, lane = t & 63;
    int b = idx >> 6, lt = (idx >> 2) & 15, ht = idx & 3;
    int l0 = lt * 64;
    int hl = ht * 256 + wv * 64 + lane;
    const unsigned short* src = yT + ((size_t)b * H_ + hl) * L_ + l0;
#pragma unroll
    for (int kk = 0; kk < 8; ++kk) {
        u16x8 v = *(const u16x8*)(src + kk * 8);
#pragma unroll
        for (int e = 0; e < 8; ++e)
            Y[((size_t)b * L_ + l0 + kk * 8 + e) * H_ + hl] = v[e];
    }
}

// ---------------------------------------------------------------------------
// K4: Z = Y @ Wt^T (+b), fused GLU epilogue (unchanged)
// ---------------------------------------------------------------------------
__global__ __launch_bounds__(256, 2) void gemm_glu(
        const __hip_bfloat16* __restrict__ Y, const __hip_bfloat16* __restrict__ Wt,
        const float* __restrict__ bv, float* __restrict__ out) {
    __shared__ char lds[32768];
    char* sA  = lds;             // [128 rows][8 chunks * 16B] = 16 KiB
    char* sBa = lds + 16384;     // [64][128B] = 8 KiB
    char* sBg = lds + 24576;     // [64][128B] = 8 KiB

    int tid = threadIdx.x, wv = tid >> 6, lane = tid & 63;
    int mb = (blockIdx.x & 127) * 128;
    int h0 = (blockIdx.x >> 7) * 64;
    int r8 = lane >> 3, c8 = lane & 7, csrc = c8 ^ r8;
    int wm = (wv >> 1) * 64, wn = (wv & 1) * 32;
    int lm = lane & 15, q = lane >> 4;

    const char* Yb = (const char*)Y;
    const char* Wb = (const char*)Wt;

    f32x4 accA[4][2], accG[4][2];
#pragma unroll
    for (int i = 0; i < 4; ++i)
#pragma unroll
        for (int j = 0; j < 2; ++j) {
            accA[i][j] = (f32x4){0.f, 0.f, 0.f, 0.f};
            accG[i][j] = (f32x4){0.f, 0.f, 0.f, 0.f};
        }

    for (int kt = 0; kt < 16; ++kt) {
        int k0b = kt * 128;
        __syncthreads();
#pragma unroll
        for (int j = 0; j < 4; ++j) {
            int i = wv * 4 + j;
            gll16(Yb + (size_t)(mb + i * 8 + r8) * 2048 + k0b + csrc * 16,
                  sA + i * 1024);
        }
#pragma unroll
        for (int j = 0; j < 2; ++j) {
            int i = wv * 2 + j;
            int n = h0 + i * 8 + r8;
            gll16(Wb + (size_t)n * 2048 + k0b + csrc * 16, sBa + i * 1024);
            gll16(Wb + (size_t)(n + 1024) * 2048 + k0b + csrc * 16, sBg + i * 1024);
        }
        __syncthreads();
#pragma unroll
        for (int kk = 0; kk < 2; ++kk) {
            int clog = kk * 4 + q;
            bf16x8 af[4], ba[2], bg[2];
#pragma unroll
            for (int mt = 0; mt < 4; ++mt) {
                int m = wm + mt * 16 + lm;
                af[mt] = *(const bf16x8*)(sA + m * 128 + ((clog ^ (m & 7)) * 16));
            }
#pragma unroll
            for (int nt = 0; nt < 2; ++nt) {
                int n = wn + nt * 16 + lm;
                int cph = (clog ^ (n & 7)) * 16;
                ba[nt] = *(const bf16x8*)(sBa + n * 128 + cph);
                bg[nt] = *(const bf16x8*)(sBg + n * 128 + cph);
            }
#pragma unroll
            for (int mt = 0; mt < 4; ++mt)
#pragma unroll
                for (int nt = 0; nt < 2; ++nt) {
                    accA[mt][nt] = __builtin_amdgcn_mfma_f32_16x16x32_bf16(
                        af[mt], ba[nt], accA[mt][nt], 0, 0, 0);
                    accG[mt][nt] = __builtin_amdgcn_mfma_f32_16x16x32_bf16(
                        af[mt], bg[nt], accG[mt][nt], 0, 0, 0);
                }
        }
    }
#pragma unroll
    for (int mt = 0; mt < 4; ++mt)
#pragma unroll
        for (int nt = 0; nt < 2; ++nt) {
            int hc = h0 + wn + nt * 16 + lm;
            float bba = bv[hc], bbg = bv[hc + 1024];
#pragma unroll
            for (int r = 0; r < 4; ++r) {
                int m = mb + wm + mt * 16 + q * 4 + r;
                float za = accA[mt][nt][r] + bba;
                float zg = accG[mt][nt][r] + bbg;
                out[(size_t)m * H_ + hc] = za / (1.0f + expf(-zg));
            }
        }
}

// ---------------------------------------------------------------------------
extern "C" void kernel_launch(void* const* d_in, const int* in_sizes, int n_in,
                              void* d_out, int out_size, void* d_ws, size_t ws_size,
                              hipStream_t stream) {
    const float* x      = (const float*)d_in[0];
    const float* log_dt = (const float*)d_in[1];
    const float* Arl    = (const float*)d_in[2];
    const float* Aim    = (const float*)d_in[3];
    const float* Cr     = (const float*)d_in[4];
    const float* Ci     = (const float*)d_in[5];
    const float* Dv     = (const float*)d_in[6];
    const float* W      = (const float*)d_in[7];
    const float* bv     = (const float*)d_in[8];
    float* out = (float*)d_out;

    char* ws = (char*)d_ws;
    // layout:
    //   [0,  32M) xTb bf16          (reused as Ybf bf16 after chunk_scan)
    //   [32M,64M) yTa bf16
    //   [64M,88M) Bt | [88M,104M) Qt | [104M,104.5M) wT | [105M,109M) Wt
    __hip_bfloat16*  xTb = (__hip_bfloat16*)ws;
    __hip_bfloat16*  yTa = (__hip_bfloat16*)(ws + (32u << 20));
    __hip_bfloat16*  Ybf = (__hip_bfloat16*)ws;
    char*            Btg = ws + (64u << 20);
    char*            Qtg = Btg + (size_t)H_ * 192 * 64 * 2;          // +24M
    float2*          wTg = (float2*)(ws + (104u << 20));
    __hip_bfloat16*  Wt  = (__hip_bfloat16*)(ws + (105u << 20));

    prep<<<2176, 256, 0, stream>>>(x, log_dt, Arl, Aim, Cr, Ci, W,
                                   xTb, (__hip_bfloat16*)Btg,
                                   (__hip_bfloat16*)Qtg, wTg, Wt);
    chunk_scan<<<4096, 256, 0, stream>>>(xTb, Btg, Qtg, wTg, Dv, yTa);
    transpose_y<<<1024, 256, 0, stream>>>(
        (const unsigned short*)yTa, (unsigned short*)Ybf);
    gemm_glu<<<2048, 256, 0, stream>>>(Ybf, Wt, bv, out);
}